// Round 1
// baseline (3171.475 us; speedup 1.0000x reference)
//
#include <hip/hip_runtime.h>

#define NN 100000
#define NE 2500000

// ---------------- kernels ----------------

__global__ void k_degrees(const int* __restrict__ src, const int* __restrict__ dst,
                          float* __restrict__ dout, float* __restrict__ din, int E) {
    int i = blockIdx.x * blockDim.x + threadIdx.x;
    if (i < E) {
        atomicAdd(&dout[src[i]], 1.0f);
        atomicAdd(&din[dst[i]], 1.0f);
    }
}

// in-place deg -> rsqrt(max(deg,1)); also produce xs[n*8+f] = x[n*7+f]*norm_out (8-padded)
__global__ void k_prep(const float* __restrict__ x, float* __restrict__ no_buf,
                       float* __restrict__ ni_buf, float* __restrict__ xs, int N) {
    int n = blockIdx.x * blockDim.x + threadIdx.x;
    if (n >= N) return;
    float no = rsqrtf(fmaxf(no_buf[n], 1.0f));
    float ni = rsqrtf(fmaxf(ni_buf[n], 1.0f));
    no_buf[n] = no;
    ni_buf[n] = ni;
#pragma unroll
    for (int f = 0; f < 7; ++f) xs[n * 8 + f] = x[n * 7 + f] * no;
    xs[n * 8 + 7] = 0.f;
}

// layer-1 edge pass: 2 threads/edge, each moves a float4 of the 8-padded 7-dim feature
__global__ void k_edge1(const int* __restrict__ src, const int* __restrict__ dst,
                        const float* __restrict__ ew, const float* __restrict__ xs,
                        float* __restrict__ agg7, int E) {
    int tid = blockIdx.x * blockDim.x + threadIdx.x;
    int e = tid >> 1, half = tid & 1;
    if (e >= E) return;
    int s = src[e], d = dst[e];
    float w = ew[e];
    const float4 v = *reinterpret_cast<const float4*>(&xs[s * 8 + half * 4]);
    float* o = &agg7[d * 8 + half * 4];
    atomicAdd(&o[0], v.x * w);
    atomicAdd(&o[1], v.y * w);
    atomicAdd(&o[2], v.z * w);
    if (!half) atomicAdd(&o[3], v.w * w);  // f=7 is padding, skip
}

// layer-1 node pass: h1s = relu((agg7*ni) @ W1 + b1) * no
__global__ void k_node1(const float* __restrict__ agg7, const float* __restrict__ ni,
                        const float* __restrict__ no, const float* __restrict__ W1,
                        const float* __restrict__ b1, float* __restrict__ h1s, int N) {
    __shared__ float sW[7 * 32];
    __shared__ float sb[32];
    for (int i = threadIdx.x; i < 7 * 32; i += blockDim.x) sW[i] = W1[i];
    if (threadIdx.x < 32) sb[threadIdx.x] = b1[threadIdx.x];
    __syncthreads();
    int n = blockIdx.x * blockDim.x + threadIdx.x;
    if (n >= N) return;
    float a[7];
    float niv = ni[n];
#pragma unroll
    for (int k = 0; k < 7; ++k) a[k] = agg7[n * 8 + k] * niv;
    float nov = no[n];
#pragma unroll
    for (int j = 0; j < 32; ++j) {
        float acc = sb[j];
#pragma unroll
        for (int k = 0; k < 7; ++k) acc += a[k] * sW[k * 32 + j];
        h1s[n * 32 + j] = fmaxf(acc, 0.f) * nov;
    }
}

// 32-wide edge pass: 8 threads/edge, float4 each
__global__ void k_edge32(const int* __restrict__ src, const int* __restrict__ dst,
                         const float* __restrict__ h, float* __restrict__ agg, int E) {
    int tid = blockIdx.x * blockDim.x + threadIdx.x;
    int e = tid >> 3, q = tid & 7;
    if (e >= E) return;
    int s = src[e], d = dst[e];
    const float4 v = *reinterpret_cast<const float4*>(&h[s * 32 + q * 4]);
    float* o = &agg[d * 32 + q * 4];
    atomicAdd(&o[0], v.x);
    atomicAdd(&o[1], v.y);
    atomicAdd(&o[2], v.z);
    atomicAdd(&o[3], v.w);
}

// generic 32->32 node pass: hs = relu((agg*ni) @ W + b) * no
__global__ void k_node32(const float* __restrict__ agg, const float* __restrict__ ni,
                         const float* __restrict__ no, const float* __restrict__ W,
                         const float* __restrict__ b, float* __restrict__ hs, int N) {
    __shared__ float sW[32 * 32];
    __shared__ float sb[32];
    for (int i = threadIdx.x; i < 1024; i += blockDim.x) sW[i] = W[i];
    if (threadIdx.x < 32) sb[threadIdx.x] = b[threadIdx.x];
    __syncthreads();
    int n = blockIdx.x * blockDim.x + threadIdx.x;
    if (n >= N) return;
    float a[32];
    float niv = ni[n];
#pragma unroll
    for (int k = 0; k < 32; k += 4) {
        float4 v = *reinterpret_cast<const float4*>(&agg[n * 32 + k]);
        a[k] = v.x * niv; a[k + 1] = v.y * niv; a[k + 2] = v.z * niv; a[k + 3] = v.w * niv;
    }
    float nov = no[n];
#pragma unroll
    for (int j = 0; j < 32; ++j) {
        float acc = sb[j];
#pragma unroll
        for (int k = 0; k < 32; ++k) acc += a[k] * sW[k * 32 + j];
        hs[n * 32 + j] = fmaxf(acc, 0.f) * nov;
    }
}

// layer-3 node pass fused with W4 pre-multiply: h4pre = (relu((agg*ni)@W3+b3)*no) @ W4
__global__ void k_node34(const float* __restrict__ agg, const float* __restrict__ ni,
                         const float* __restrict__ no, const float* __restrict__ W3,
                         const float* __restrict__ b3, const float* __restrict__ W4,
                         float2* __restrict__ h4pre, int N) {
    __shared__ float sW[32 * 32];
    __shared__ float sb[32];
    __shared__ float sW4[64];
    for (int i = threadIdx.x; i < 1024; i += blockDim.x) sW[i] = W3[i];
    if (threadIdx.x < 32) sb[threadIdx.x] = b3[threadIdx.x];
    if (threadIdx.x < 64) sW4[threadIdx.x] = W4[threadIdx.x];
    __syncthreads();
    int n = blockIdx.x * blockDim.x + threadIdx.x;
    if (n >= N) return;
    float a[32];
    float niv = ni[n];
#pragma unroll
    for (int k = 0; k < 32; k += 4) {
        float4 v = *reinterpret_cast<const float4*>(&agg[n * 32 + k]);
        a[k] = v.x * niv; a[k + 1] = v.y * niv; a[k + 2] = v.z * niv; a[k + 3] = v.w * niv;
    }
    float nov = no[n];
    float px = 0.f, py = 0.f;
#pragma unroll
    for (int j = 0; j < 32; ++j) {
        float acc = sb[j];
#pragma unroll
        for (int k = 0; k < 32; ++k) acc += a[k] * sW[k * 32 + j];
        float t = fmaxf(acc, 0.f) * nov;
        px += t * sW4[j * 2 + 0];
        py += t * sW4[j * 2 + 1];
    }
    h4pre[n] = make_float2(px, py);
}

// layer-4 edge pass in 2-dim
__global__ void k_edge4(const int* __restrict__ src, const int* __restrict__ dst,
                        const float2* __restrict__ h4pre, float* __restrict__ agg2, int E) {
    int e = blockIdx.x * blockDim.x + threadIdx.x;
    if (e >= E) return;
    float2 v = h4pre[src[e]];
    int d = dst[e];
    atomicAdd(&agg2[d * 2 + 0], v.x);
    atomicAdd(&agg2[d * 2 + 1], v.y);
}

// mean pooling: graph_id is sorted -> one wave per graph, binary-search range, no atomics.
// out[g] = sum(agg2[n]*ni[n]) / max(cnt,1) + b4 * (cnt/max(cnt,1))
__global__ void k_pool(const float* __restrict__ agg2, const float* __restrict__ ni,
                       const int* __restrict__ gid, const float* __restrict__ b4,
                       float* __restrict__ out, int N) {
    int g = blockIdx.x;
    int lo = 0, hi = N;
    while (lo < hi) { int m = (lo + hi) >> 1; if (gid[m] < g) lo = m + 1; else hi = m; }
    int start = lo;
    int lo2 = start, hi2 = N;
    while (lo2 < hi2) { int m = (lo2 + hi2) >> 1; if (gid[m] < g + 1) lo2 = m + 1; else hi2 = m; }
    int end = lo2;
    float sx = 0.f, sy = 0.f;
    for (int n = start + threadIdx.x; n < end; n += 64) {
        float w = ni[n];
        sx += agg2[n * 2 + 0] * w;
        sy += agg2[n * 2 + 1] * w;
    }
#pragma unroll
    for (int off = 32; off; off >>= 1) {
        sx += __shfl_down(sx, off, 64);
        sy += __shfl_down(sy, off, 64);
    }
    if (threadIdx.x == 0) {
        int cnt = end - start;
        float inv = 1.0f / fmaxf((float)cnt, 1.0f);
        float scale = (float)cnt * inv;  // 0 if empty, else 1
        out[g * 2 + 0] = sx * inv + b4[0] * scale;
        out[g * 2 + 1] = sy * inv + b4[1] * scale;
    }
}

// ---------------- launch ----------------

extern "C" void kernel_launch(void* const* d_in, const int* in_sizes, int n_in,
                              void* d_out, int out_size, void* d_ws, size_t ws_size,
                              hipStream_t stream) {
    const float* x   = (const float*)d_in[0];
    const float* e   = (const float*)d_in[1];
    const float* W1  = (const float*)d_in[2];
    const float* b1  = (const float*)d_in[3];
    const float* W2  = (const float*)d_in[4];
    const float* b2  = (const float*)d_in[5];
    const float* W3  = (const float*)d_in[6];
    const float* b3  = (const float*)d_in[7];
    const float* W4  = (const float*)d_in[8];
    const float* b4  = (const float*)d_in[9];
    const int*   src = (const int*)d_in[10];
    const int*   dst = (const int*)d_in[11];
    const int*   gid = (const int*)d_in[12];
    float* out = (float*)d_out;

    const int N = NN, E = NE;
    const int G = out_size / 2;

    // workspace layout (floats); all offsets are multiples of N*4 bytes (16B-aligned)
    float* ws = (float*)d_ws;
    float* no_buf = ws;                 // N      (deg_out -> norm_out in place)
    float* ni_buf = ws + (size_t)N;     // N
    float* agg7   = ws + (size_t)2  * N; // 8N
    float* agg32a = ws + (size_t)10 * N; // 32N
    float* agg32b = ws + (size_t)42 * N; // 32N
    float* agg2   = ws + (size_t)74 * N; // 2N
    float* xs     = ws + (size_t)76 * N; // 8N
    float* h1s    = ws + (size_t)84 * N; // 32N
    float* h2s    = ws + (size_t)116 * N; // 32N
    float2* h4pre = (float2*)(ws + (size_t)148 * N); // 2N
    // total 150N floats = 60 MB

    // zero the accumulation region [0 .. 76N) in one shot
    hipMemsetAsync(ws, 0, (size_t)76 * N * sizeof(float), stream);

    const int B = 256;
    k_degrees<<<(E + B - 1) / B, B, 0, stream>>>(src, dst, no_buf, ni_buf, E);
    k_prep<<<(N + B - 1) / B, B, 0, stream>>>(x, no_buf, ni_buf, xs, N);

    k_edge1<<<(2 * E + B - 1) / B, B, 0, stream>>>(src, dst, e, xs, agg7, E);
    k_node1<<<(N + B - 1) / B, B, 0, stream>>>(agg7, ni_buf, no_buf, W1, b1, h1s, N);

    k_edge32<<<(8 * E + B - 1) / B, B, 0, stream>>>(src, dst, h1s, agg32a, E);
    k_node32<<<(N + B - 1) / B, B, 0, stream>>>(agg32a, ni_buf, no_buf, W2, b2, h2s, N);

    k_edge32<<<(8 * E + B - 1) / B, B, 0, stream>>>(src, dst, h2s, agg32b, E);
    k_node34<<<(N + B - 1) / B, B, 0, stream>>>(agg32b, ni_buf, no_buf, W3, b3, W4, h4pre, N);

    k_edge4<<<(E + B - 1) / B, B, 0, stream>>>(src, dst, h4pre, agg2, E);

    k_pool<<<G, 64, 0, stream>>>(agg2, ni_buf, gid, b4, out, N);
}

// Round 2
// 861.652 us; speedup vs baseline: 3.6807x; 3.6807x over previous
//
#include <hip/hip_runtime.h>

#define NN 100000
#define NE 2500000
#define NB_SCAN ((NN + 255) / 256)   // 391 scan blocks

// ---------------- CSR build ----------------

__global__ void k_hist(const int* __restrict__ src, const int* __restrict__ dst,
                       int* __restrict__ cnt_out, int* __restrict__ cnt_in, int E) {
    int i = blockIdx.x * blockDim.x + threadIdx.x;
    if (i < E) {
        atomicAdd(&cnt_out[src[i]], 1);
        atomicAdd(&cnt_in[dst[i]], 1);
    }
}

// per-block inclusive scan of cnt_in -> partial exclusive row_ptr + block sums
__global__ void k_scan_blocks(const int* __restrict__ cnt, int* __restrict__ row_ptr,
                              int* __restrict__ bsum, int N) {
    __shared__ int sh[256];
    int i = blockIdx.x * 256 + threadIdx.x;
    int v = (i < N) ? cnt[i] : 0;
    sh[threadIdx.x] = v;
    __syncthreads();
#pragma unroll
    for (int off = 1; off < 256; off <<= 1) {
        int t = (threadIdx.x >= off) ? sh[threadIdx.x - off] : 0;
        __syncthreads();
        sh[threadIdx.x] += t;
        __syncthreads();
    }
    if (i < N) row_ptr[i] = sh[threadIdx.x] - v;  // exclusive, pre-offset
    if (threadIdx.x == 255) bsum[blockIdx.x] = sh[255];
}

// single-block scan of the block sums -> exclusive offsets
__global__ void k_scan_top(const int* __restrict__ bsum, int* __restrict__ bsum_ex, int NB) {
    __shared__ int sh[512];
    int tid = threadIdx.x;
    int v = (tid < NB) ? bsum[tid] : 0;
    sh[tid] = v;
    __syncthreads();
#pragma unroll
    for (int off = 1; off < 512; off <<= 1) {
        int t = (tid >= off) ? sh[tid - off] : 0;
        __syncthreads();
        sh[tid] += t;
        __syncthreads();
    }
    if (tid < NB) bsum_ex[tid] = sh[tid] - v;
}

// add block offsets; init cursor; set row_ptr[N]=E
__global__ void k_scan_add(int* __restrict__ row_ptr, const int* __restrict__ bsum_ex,
                           int* __restrict__ cursor, int N, int E) {
    int i = blockIdx.x * blockDim.x + threadIdx.x;
    if (i < N) {
        int r = row_ptr[i] + bsum_ex[i >> 8];
        row_ptr[i] = r;
        cursor[i] = r;
    } else if (i == N) {
        row_ptr[N] = E;
    }
}

__global__ void k_scatter(const int* __restrict__ src, const int* __restrict__ dst,
                          const float* __restrict__ ew, int* __restrict__ cursor,
                          int* __restrict__ csr_src, float* __restrict__ csr_w, int E) {
    int e = blockIdx.x * blockDim.x + threadIdx.x;
    if (e < E) {
        int pos = atomicAdd(&cursor[dst[e]], 1);
        csr_src[pos] = src[e];
        csr_w[pos] = ew[e];
    }
}

// norms from degree counts; xs[n*8+f] = x[n*7+f]*norm_out (8-padded)
__global__ void k_prep(const float* __restrict__ x, const int* __restrict__ cnt_out,
                       const int* __restrict__ cnt_in, float* __restrict__ no,
                       float* __restrict__ ni, float* __restrict__ xs, int N) {
    int n = blockIdx.x * blockDim.x + threadIdx.x;
    if (n >= N) return;
    float nov = rsqrtf(fmaxf((float)cnt_out[n], 1.0f));
    float niv = rsqrtf(fmaxf((float)cnt_in[n], 1.0f));
    no[n] = nov;
    ni[n] = niv;
#pragma unroll
    for (int f = 0; f < 7; ++f) xs[n * 8 + f] = x[n * 7 + f] * nov;
    xs[n * 8 + 7] = 0.f;
}

// ---------------- fused layers (gather, no atomics) ----------------

// layer 1: 8 lanes/node gather-aggregate (weighted), then 7->32 matmul epilogue.
// h1s = relu((agg*ni) @ W1 + b1) * no
__global__ __launch_bounds__(256) void k_layer1(
    const int* __restrict__ rp, const int* __restrict__ csr_src, const float* __restrict__ csr_w,
    const float* __restrict__ xs, const float* __restrict__ ni, const float* __restrict__ no,
    const float* __restrict__ W1, const float* __restrict__ b1, float* __restrict__ h1s, int N) {
    __shared__ float sW[7 * 32];
    __shared__ float sb[32];
    __shared__ float sh7[32][8];
    for (int i = threadIdx.x; i < 7 * 32; i += 256) sW[i] = W1[i];
    if (threadIdx.x < 32) sb[threadIdx.x] = b1[threadIdx.x];

    int g = threadIdx.x >> 3, lane = threadIdx.x & 7;
    int node = blockIdx.x * 32 + g;
    float acc = 0.f;
    if (node < N) {
        int beg = rp[node], end = rp[node + 1];
        for (int j = beg; j < end; ++j) {
            int s = csr_src[j];
            float w = csr_w[j];
            acc += xs[s * 8 + lane] * w;
        }
        acc *= ni[node];
    }
    sh7[g][lane] = acc;
    __syncthreads();

    int g2 = threadIdx.x >> 5, l32 = threadIdx.x & 31;
#pragma unroll
    for (int t = 0; t < 4; ++t) {
        int nl = t * 8 + g2;
        int node2 = blockIdx.x * 32 + nl;
        if (node2 < N) {
            float o = sb[l32];
#pragma unroll
            for (int k = 0; k < 7; ++k) o += sh7[nl][k] * sW[k * 32 + l32];
            h1s[node2 * 32 + l32] = fmaxf(o, 0.f) * no[node2];
        }
    }
}

// 32-wide layer: 32 lanes/node, coalesced 128B gather per edge, fused 32x32 matmul.
// h_out = relu((agg*ni) @ W + b) * no
__global__ __launch_bounds__(256) void k_layer32(
    const int* __restrict__ rp, const int* __restrict__ csr_src, const float* __restrict__ h_in,
    const float* __restrict__ ni, const float* __restrict__ no, const float* __restrict__ W,
    const float* __restrict__ b, float* __restrict__ h_out, int N) {
    __shared__ float sW[32 * 32];
    __shared__ float sb[32];
    __shared__ float shv[8][32];
    for (int i = threadIdx.x; i < 1024; i += 256) sW[i] = W[i];
    if (threadIdx.x < 32) sb[threadIdx.x] = b[threadIdx.x];

    int g = threadIdx.x >> 5, lane = threadIdx.x & 31;
    int node = blockIdx.x * 8 + g;
    float acc = 0.f;
    if (node < N) {
        int beg = rp[node], end = rp[node + 1];
        for (int j = beg; j < end; ++j) {
            int s = csr_src[j];
            acc += h_in[s * 32 + lane];
        }
        acc *= ni[node];
    }
    shv[g][lane] = acc;
    __syncthreads();
    if (node < N) {
        float o = sb[lane];
#pragma unroll
        for (int k = 0; k < 32; ++k) o += shv[g][k] * sW[k * 32 + lane];
        h_out[node * 32 + lane] = fmaxf(o, 0.f) * no[node];
    }
}

// layer 3 + W4 pre-multiply: h4pre = (relu((agg*ni)@W3+b3)*no) @ W4   [per node, 2-dim]
__global__ __launch_bounds__(256) void k_layer34(
    const int* __restrict__ rp, const int* __restrict__ csr_src, const float* __restrict__ h_in,
    const float* __restrict__ ni, const float* __restrict__ no, const float* __restrict__ W3,
    const float* __restrict__ b3, const float* __restrict__ W4, float2* __restrict__ h4pre, int N) {
    __shared__ float sW[32 * 32];
    __shared__ float sb[32];
    __shared__ float sW4[64];
    __shared__ float shv[8][32];
    for (int i = threadIdx.x; i < 1024; i += 256) sW[i] = W3[i];
    if (threadIdx.x < 32) sb[threadIdx.x] = b3[threadIdx.x];
    if (threadIdx.x < 64) sW4[threadIdx.x] = W4[threadIdx.x];

    int g = threadIdx.x >> 5, lane = threadIdx.x & 31;
    int node = blockIdx.x * 8 + g;
    float acc = 0.f;
    if (node < N) {
        int beg = rp[node], end = rp[node + 1];
        for (int j = beg; j < end; ++j) {
            int s = csr_src[j];
            acc += h_in[s * 32 + lane];
        }
        acc *= ni[node];
    }
    shv[g][lane] = acc;
    __syncthreads();
    if (node < N) {
        float o = sb[lane];
#pragma unroll
        for (int k = 0; k < 32; ++k) o += shv[g][k] * sW[k * 32 + lane];
        float t = fmaxf(o, 0.f) * no[node];
        float px = t * sW4[lane * 2 + 0];
        float py = t * sW4[lane * 2 + 1];
#pragma unroll
        for (int off = 16; off; off >>= 1) {
            px += __shfl_xor(px, off, 32);
            py += __shfl_xor(py, off, 32);
        }
        if (lane == 0) h4pre[node] = make_float2(px, py);
    }
}

// layer-4 aggregation in 2-dim, one thread/node; stores agg*ni
__global__ void k_agg4(const int* __restrict__ rp, const int* __restrict__ csr_src,
                       const float2* __restrict__ h4pre, const float* __restrict__ ni,
                       float2* __restrict__ agg2, int N) {
    int n = blockIdx.x * blockDim.x + threadIdx.x;
    if (n >= N) return;
    float ax = 0.f, ay = 0.f;
    int beg = rp[n], end = rp[n + 1];
    for (int j = beg; j < end; ++j) {
        float2 v = h4pre[csr_src[j]];
        ax += v.x;
        ay += v.y;
    }
    float w = ni[n];
    agg2[n] = make_float2(ax * w, ay * w);
}

// mean pooling: gid sorted -> one wave/graph, binary-search range
__global__ void k_pool(const float2* __restrict__ agg2, const int* __restrict__ gid,
                       const float* __restrict__ b4, float* __restrict__ out, int N) {
    int g = blockIdx.x;
    int lo = 0, hi = N;
    while (lo < hi) { int m = (lo + hi) >> 1; if (gid[m] < g) lo = m + 1; else hi = m; }
    int start = lo;
    int lo2 = start, hi2 = N;
    while (lo2 < hi2) { int m = (lo2 + hi2) >> 1; if (gid[m] < g + 1) lo2 = m + 1; else hi2 = m; }
    int end = lo2;
    float sx = 0.f, sy = 0.f;
    for (int n = start + threadIdx.x; n < end; n += 64) {
        float2 v = agg2[n];
        sx += v.x;
        sy += v.y;
    }
#pragma unroll
    for (int off = 32; off; off >>= 1) {
        sx += __shfl_down(sx, off, 64);
        sy += __shfl_down(sy, off, 64);
    }
    if (threadIdx.x == 0) {
        int cnt = end - start;
        float inv = 1.0f / fmaxf((float)cnt, 1.0f);
        float scale = (float)cnt * inv;  // 0 if empty, else 1
        out[g * 2 + 0] = sx * inv + b4[0] * scale;
        out[g * 2 + 1] = sy * inv + b4[1] * scale;
    }
}

// ---------------- launch ----------------

extern "C" void kernel_launch(void* const* d_in, const int* in_sizes, int n_in,
                              void* d_out, int out_size, void* d_ws, size_t ws_size,
                              hipStream_t stream) {
    const float* x   = (const float*)d_in[0];
    const float* e   = (const float*)d_in[1];
    const float* W1  = (const float*)d_in[2];
    const float* b1  = (const float*)d_in[3];
    const float* W2  = (const float*)d_in[4];
    const float* b2  = (const float*)d_in[5];
    const float* W3  = (const float*)d_in[6];
    const float* b3  = (const float*)d_in[7];
    const float* W4  = (const float*)d_in[8];
    const float* b4  = (const float*)d_in[9];
    const int*   src = (const int*)d_in[10];
    const int*   dst = (const int*)d_in[11];
    const int*   gid = (const int*)d_in[12];
    float* out = (float*)d_out;

    const int N = NN, E = NE;
    const int G = out_size / 2;

    // workspace layout: ints first, then edge arrays, then float buffers.
    // all offsets multiple of 4 elements (16B aligned); N,E divisible by 4.
    int* ws_i = (int*)d_ws;
    int* cnt_out = ws_i;                       // N
    int* cnt_in  = ws_i + (size_t)N;           // N
    int* row_ptr = ws_i + (size_t)2 * N;       // N+1 (alloc N+4)
    int* cursor  = ws_i + (size_t)3 * N + 4;   // N
    int* bsum    = ws_i + (size_t)4 * N + 4;   // 512
    int* bsum_ex = ws_i + (size_t)4 * N + 516; // 512 (pad to 4N+1028 -> round 4N+1032)
    int* csr_src = ws_i + (size_t)4 * N + 1032;          // E
    float* csr_w = (float*)(ws_i + (size_t)4 * N + 1032 + E); // E

    float* fbase = (float*)(ws_i + (size_t)4 * N + 1032 + 2 * (size_t)E);
    float* no_b  = fbase;                      // N
    float* ni_b  = fbase + (size_t)N;          // N
    float* xs    = fbase + (size_t)2 * N;      // 8N
    float* h1s   = fbase + (size_t)10 * N;     // 32N
    float* h2s   = fbase + (size_t)42 * N;     // 32N
    float2* h4pre = (float2*)(fbase + (size_t)74 * N); // 2N
    float2* agg2  = (float2*)(fbase + (size_t)76 * N); // 2N

    // zero only the histograms
    hipMemsetAsync(ws_i, 0, (size_t)2 * N * sizeof(int), stream);

    const int B = 256;
    k_hist<<<(E + B - 1) / B, B, 0, stream>>>(src, dst, cnt_out, cnt_in, E);
    k_scan_blocks<<<NB_SCAN, 256, 0, stream>>>(cnt_in, row_ptr, bsum, N);
    k_scan_top<<<1, 512, 0, stream>>>(bsum, bsum_ex, NB_SCAN);
    k_scan_add<<<(N + 1 + B - 1) / B, B, 0, stream>>>(row_ptr, bsum_ex, cursor, N, E);
    k_scatter<<<(E + B - 1) / B, B, 0, stream>>>(src, dst, e, cursor, csr_src, csr_w, E);
    k_prep<<<(N + B - 1) / B, B, 0, stream>>>(x, cnt_out, cnt_in, no_b, ni_b, xs, N);

    k_layer1<<<(N + 31) / 32, 256, 0, stream>>>(row_ptr, csr_src, csr_w, xs, ni_b, no_b, W1, b1, h1s, N);
    k_layer32<<<(N + 7) / 8, 256, 0, stream>>>(row_ptr, csr_src, h1s, ni_b, no_b, W2, b2, h2s, N);
    k_layer34<<<(N + 7) / 8, 256, 0, stream>>>(row_ptr, csr_src, h2s, ni_b, no_b, W3, b3, W4, h4pre, N);
    k_agg4<<<(N + B - 1) / B, B, 0, stream>>>(row_ptr, csr_src, h4pre, ni_b, agg2, N);
    k_pool<<<G, 64, 0, stream>>>(agg2, gid, b4, out, N);
}

// Round 3
// 762.649 us; speedup vs baseline: 4.1585x; 1.1298x over previous
//
#include <hip/hip_runtime.h>

#define NN 100000
#define NE 2500000
#define NB_SCAN ((NN + 255) / 256)   // 391 scan blocks

// ---------------- CSR build ----------------

__global__ void k_hist(const int* __restrict__ src, const int* __restrict__ dst,
                       int* __restrict__ cnt_out, int* __restrict__ cnt_in, int E) {
    int i = blockIdx.x * blockDim.x + threadIdx.x;
    if (i < E) {
        atomicAdd(&cnt_out[src[i]], 1);
        atomicAdd(&cnt_in[dst[i]], 1);
    }
}

// per-block inclusive scan of cnt_in -> partial exclusive row_ptr + block sums
__global__ void k_scan_blocks(const int* __restrict__ cnt, int* __restrict__ row_ptr,
                              int* __restrict__ bsum, int N) {
    __shared__ int sh[256];
    int i = blockIdx.x * 256 + threadIdx.x;
    int v = (i < N) ? cnt[i] : 0;
    sh[threadIdx.x] = v;
    __syncthreads();
#pragma unroll
    for (int off = 1; off < 256; off <<= 1) {
        int t = (threadIdx.x >= off) ? sh[threadIdx.x - off] : 0;
        __syncthreads();
        sh[threadIdx.x] += t;
        __syncthreads();
    }
    if (i < N) row_ptr[i] = sh[threadIdx.x] - v;  // exclusive, pre-offset
    if (threadIdx.x == 255) bsum[blockIdx.x] = sh[255];
}

// single-block scan of the block sums -> exclusive offsets
__global__ void k_scan_top(const int* __restrict__ bsum, int* __restrict__ bsum_ex, int NB) {
    __shared__ int sh[512];
    int tid = threadIdx.x;
    int v = (tid < NB) ? bsum[tid] : 0;
    sh[tid] = v;
    __syncthreads();
#pragma unroll
    for (int off = 1; off < 512; off <<= 1) {
        int t = (tid >= off) ? sh[tid - off] : 0;
        __syncthreads();
        sh[tid] += t;
        __syncthreads();
    }
    if (tid < NB) bsum_ex[tid] = sh[tid] - v;
}

// add block offsets; init cursor; row_ptr[N]=E; also fused prep:
// norms from degrees + xs[n*8+f] = x[n*7+f]*norm_out (8-padded)
__global__ void k_scan_add_prep(int* __restrict__ row_ptr, const int* __restrict__ bsum_ex,
                                int* __restrict__ cursor, const int* __restrict__ cnt_out,
                                const int* __restrict__ cnt_in, const float* __restrict__ x,
                                float* __restrict__ no, float* __restrict__ ni,
                                float* __restrict__ xs, int N, int E) {
    int i = blockIdx.x * blockDim.x + threadIdx.x;
    if (i < N) {
        int r = row_ptr[i] + bsum_ex[i >> 8];
        row_ptr[i] = r;
        cursor[i] = r;
        float nov = rsqrtf(fmaxf((float)cnt_out[i], 1.0f));
        float niv = rsqrtf(fmaxf((float)cnt_in[i], 1.0f));
        no[i] = nov;
        ni[i] = niv;
#pragma unroll
        for (int f = 0; f < 7; ++f) xs[i * 8 + f] = x[i * 7 + f] * nov;
        xs[i * 8 + 7] = 0.f;
    } else if (i == N) {
        row_ptr[N] = E;
    }
}

// single 8B packed store per edge: (src, edge_weight)
__global__ void k_scatter(const int* __restrict__ src, const int* __restrict__ dst,
                          const float* __restrict__ ew, int* __restrict__ cursor,
                          int2* __restrict__ csr2, int E) {
    int e = blockIdx.x * blockDim.x + threadIdx.x;
    if (e < E) {
        int pos = atomicAdd(&cursor[dst[e]], 1);
        csr2[pos] = make_int2(src[e], __float_as_int(ew[e]));
    }
}

// ---------------- fused layers (gather, no atomics) ----------------

// layer 1: 8 lanes/node gather-aggregate (weighted), then 7->32 matmul epilogue.
// h1s = relu((agg*ni) @ W1 + b1) * no
__global__ __launch_bounds__(256) void k_layer1(
    const int* __restrict__ rp, const int2* __restrict__ csr2,
    const float* __restrict__ xs, const float* __restrict__ ni, const float* __restrict__ no,
    const float* __restrict__ W1, const float* __restrict__ b1, float* __restrict__ h1s, int N) {
    __shared__ float sW[7 * 32];
    __shared__ float sb[32];
    __shared__ float sh7[32][8];
    for (int i = threadIdx.x; i < 7 * 32; i += 256) sW[i] = W1[i];
    if (threadIdx.x < 32) sb[threadIdx.x] = b1[threadIdx.x];

    int g = threadIdx.x >> 3, lane = threadIdx.x & 7;
    int node = blockIdx.x * 32 + g;
    float acc = 0.f;
    if (node < N) {
        int beg = rp[node], end = rp[node + 1];
        for (int j0 = beg; j0 < end; j0 += 8) {
            int ms = 0; float mw = 0.f;
            if (j0 + lane < end) {
                int2 t = csr2[j0 + lane];
                ms = t.x;
                mw = __int_as_float(t.y);
            }
            int m = end - j0; if (m > 8) m = 8;
            for (int k = 0; k < m; ++k) {
                int s = __shfl(ms, k, 8);
                float w = __shfl(mw, k, 8);
                acc += xs[s * 8 + lane] * w;
            }
        }
        acc *= ni[node];
    }
    sh7[g][lane] = acc;
    __syncthreads();

    int g2 = threadIdx.x >> 5, l32 = threadIdx.x & 31;
#pragma unroll
    for (int t = 0; t < 4; ++t) {
        int nl = t * 8 + g2;
        int node2 = blockIdx.x * 32 + nl;
        if (node2 < N) {
            float o = sb[l32];
#pragma unroll
            for (int k = 0; k < 7; ++k) o += sh7[nl][k] * sW[k * 32 + l32];
            h1s[node2 * 32 + l32] = fmaxf(o, 0.f) * no[node2];
        }
    }
}

// 32-wide layer: 32 lanes/node, shfl-batched CSR walk, coalesced 128B gather per edge,
// fused 32x32 matmul. h_out = relu((agg*ni) @ W + b) * no
__global__ __launch_bounds__(256) void k_layer32(
    const int* __restrict__ rp, const int2* __restrict__ csr2, const float* __restrict__ h_in,
    const float* __restrict__ ni, const float* __restrict__ no, const float* __restrict__ W,
    const float* __restrict__ b, float* __restrict__ h_out, int N) {
    __shared__ float sW[32 * 32];
    __shared__ float sb[32];
    __shared__ float shv[8][32];
    for (int i = threadIdx.x; i < 1024; i += 256) sW[i] = W[i];
    if (threadIdx.x < 32) sb[threadIdx.x] = b[threadIdx.x];

    int g = threadIdx.x >> 5, lane = threadIdx.x & 31;
    int node = blockIdx.x * 8 + g;
    float acc = 0.f;
    if (node < N) {
        int beg = rp[node], end = rp[node + 1];
        for (int j0 = beg; j0 < end; j0 += 32) {
            int ms = (j0 + lane < end) ? csr2[j0 + lane].x : 0;
            int m = end - j0; if (m > 32) m = 32;
            for (int k = 0; k < m; ++k) {
                int s = __shfl(ms, k, 32);
                acc += h_in[s * 32 + lane];
            }
        }
        acc *= ni[node];
    }
    shv[g][lane] = acc;
    __syncthreads();
    if (node < N) {
        float o = sb[lane];
#pragma unroll
        for (int k = 0; k < 32; ++k) o += shv[g][k] * sW[k * 32 + lane];
        h_out[node * 32 + lane] = fmaxf(o, 0.f) * no[node];
    }
}

// layer 3 + W4 pre-multiply: h4pre = (relu((agg*ni)@W3+b3)*no) @ W4   [per node, 2-dim]
__global__ __launch_bounds__(256) void k_layer34(
    const int* __restrict__ rp, const int2* __restrict__ csr2, const float* __restrict__ h_in,
    const float* __restrict__ ni, const float* __restrict__ no, const float* __restrict__ W3,
    const float* __restrict__ b3, const float* __restrict__ W4, float2* __restrict__ h4pre, int N) {
    __shared__ float sW[32 * 32];
    __shared__ float sb[32];
    __shared__ float sW4[64];
    __shared__ float shv[8][32];
    for (int i = threadIdx.x; i < 1024; i += 256) sW[i] = W3[i];
    if (threadIdx.x < 32) sb[threadIdx.x] = b3[threadIdx.x];
    if (threadIdx.x < 64) sW4[threadIdx.x] = W4[threadIdx.x];

    int g = threadIdx.x >> 5, lane = threadIdx.x & 31;
    int node = blockIdx.x * 8 + g;
    float acc = 0.f;
    if (node < N) {
        int beg = rp[node], end = rp[node + 1];
        for (int j0 = beg; j0 < end; j0 += 32) {
            int ms = (j0 + lane < end) ? csr2[j0 + lane].x : 0;
            int m = end - j0; if (m > 32) m = 32;
            for (int k = 0; k < m; ++k) {
                int s = __shfl(ms, k, 32);
                acc += h_in[s * 32 + lane];
            }
        }
        acc *= ni[node];
    }
    shv[g][lane] = acc;
    __syncthreads();
    if (node < N) {
        float o = sb[lane];
#pragma unroll
        for (int k = 0; k < 32; ++k) o += shv[g][k] * sW[k * 32 + lane];
        float t = fmaxf(o, 0.f) * no[node];
        float px = t * sW4[lane * 2 + 0];
        float py = t * sW4[lane * 2 + 1];
#pragma unroll
        for (int off = 16; off; off >>= 1) {
            px += __shfl_xor(px, off, 32);
            py += __shfl_xor(py, off, 32);
        }
        if (lane == 0) h4pre[node] = make_float2(px, py);
    }
}

// layer-4 aggregation in 2-dim, one thread/node; stores agg*ni
__global__ void k_agg4(const int* __restrict__ rp, const int2* __restrict__ csr2,
                       const float2* __restrict__ h4pre, const float* __restrict__ ni,
                       float2* __restrict__ agg2, int N) {
    int n = blockIdx.x * blockDim.x + threadIdx.x;
    if (n >= N) return;
    float ax = 0.f, ay = 0.f;
    int beg = rp[n], end = rp[n + 1];
    for (int j = beg; j < end; ++j) {
        float2 v = h4pre[csr2[j].x];
        ax += v.x;
        ay += v.y;
    }
    float w = ni[n];
    agg2[n] = make_float2(ax * w, ay * w);
}

// mean pooling: gid sorted -> one wave/graph, binary-search range
__global__ void k_pool(const float2* __restrict__ agg2, const int* __restrict__ gid,
                       const float* __restrict__ b4, float* __restrict__ out, int N) {
    int g = blockIdx.x;
    int lo = 0, hi = N;
    while (lo < hi) { int m = (lo + hi) >> 1; if (gid[m] < g) lo = m + 1; else hi = m; }
    int start = lo;
    int lo2 = start, hi2 = N;
    while (lo2 < hi2) { int m = (lo2 + hi2) >> 1; if (gid[m] < g + 1) lo2 = m + 1; else hi2 = m; }
    int end = lo2;
    float sx = 0.f, sy = 0.f;
    for (int n = start + threadIdx.x; n < end; n += 64) {
        float2 v = agg2[n];
        sx += v.x;
        sy += v.y;
    }
#pragma unroll
    for (int off = 32; off; off >>= 1) {
        sx += __shfl_down(sx, off, 64);
        sy += __shfl_down(sy, off, 64);
    }
    if (threadIdx.x == 0) {
        int cnt = end - start;
        float inv = 1.0f / fmaxf((float)cnt, 1.0f);
        float scale = (float)cnt * inv;  // 0 if empty, else 1
        out[g * 2 + 0] = sx * inv + b4[0] * scale;
        out[g * 2 + 1] = sy * inv + b4[1] * scale;
    }
}

// ---------------- launch ----------------

extern "C" void kernel_launch(void* const* d_in, const int* in_sizes, int n_in,
                              void* d_out, int out_size, void* d_ws, size_t ws_size,
                              hipStream_t stream) {
    const float* x   = (const float*)d_in[0];
    const float* e   = (const float*)d_in[1];
    const float* W1  = (const float*)d_in[2];
    const float* b1  = (const float*)d_in[3];
    const float* W2  = (const float*)d_in[4];
    const float* b2  = (const float*)d_in[5];
    const float* W3  = (const float*)d_in[6];
    const float* b3  = (const float*)d_in[7];
    const float* W4  = (const float*)d_in[8];
    const float* b4  = (const float*)d_in[9];
    const int*   src = (const int*)d_in[10];
    const int*   dst = (const int*)d_in[11];
    const int*   gid = (const int*)d_in[12];
    float* out = (float*)d_out;

    const int N = NN, E = NE;
    const int G = out_size / 2;

    // workspace layout: ints, then packed csr (int2), then float buffers.
    int* ws_i = (int*)d_ws;
    int* cnt_out = ws_i;                       // N
    int* cnt_in  = ws_i + (size_t)N;           // N
    int* row_ptr = ws_i + (size_t)2 * N;       // N+1 (alloc N+4)
    int* cursor  = ws_i + (size_t)3 * N + 4;   // N
    int* bsum    = ws_i + (size_t)4 * N + 4;   // 512
    int* bsum_ex = ws_i + (size_t)4 * N + 516; // 512 -> next at 4N+1028, round to 4N+1032
    int2* csr2   = (int2*)(ws_i + (size_t)4 * N + 1032); // E int2 (8B each)

    float* fbase = (float*)(ws_i + (size_t)4 * N + 1032 + 2 * (size_t)E);
    float* no_b  = fbase;                      // N
    float* ni_b  = fbase + (size_t)N;          // N
    float* xs    = fbase + (size_t)2 * N;      // 8N
    float* h1s   = fbase + (size_t)10 * N;     // 32N
    float* h2s   = fbase + (size_t)42 * N;     // 32N
    float2* h4pre = (float2*)(fbase + (size_t)74 * N); // 2N
    float2* agg2  = (float2*)(fbase + (size_t)76 * N); // 2N

    // zero only the histograms
    hipMemsetAsync(ws_i, 0, (size_t)2 * N * sizeof(int), stream);

    const int B = 256;
    k_hist<<<(E + B - 1) / B, B, 0, stream>>>(src, dst, cnt_out, cnt_in, E);
    k_scan_blocks<<<NB_SCAN, 256, 0, stream>>>(cnt_in, row_ptr, bsum, N);
    k_scan_top<<<1, 512, 0, stream>>>(bsum, bsum_ex, NB_SCAN);
    k_scan_add_prep<<<(N + 1 + B - 1) / B, B, 0, stream>>>(row_ptr, bsum_ex, cursor,
                                                           cnt_out, cnt_in, x, no_b, ni_b, xs, N, E);
    k_scatter<<<(E + B - 1) / B, B, 0, stream>>>(src, dst, e, cursor, csr2, E);

    k_layer1<<<(N + 31) / 32, 256, 0, stream>>>(row_ptr, csr2, xs, ni_b, no_b, W1, b1, h1s, N);
    k_layer32<<<(N + 7) / 8, 256, 0, stream>>>(row_ptr, csr2, h1s, ni_b, no_b, W2, b2, h2s, N);
    k_layer34<<<(N + 7) / 8, 256, 0, stream>>>(row_ptr, csr2, h2s, ni_b, no_b, W3, b3, W4, h4pre, N);
    k_agg4<<<(N + B - 1) / B, B, 0, stream>>>(row_ptr, csr2, h4pre, ni_b, agg2, N);
    k_pool<<<G, 64, 0, stream>>>(agg2, gid, b4, out, N);
}